// Round 14
// baseline (244.189 us; speedup 1.0000x reference)
//
#include <hip/hip_runtime.h>
#include <float.h>
#include <limits.h>

#define NB     16
#define QLEN   32
#define HDIM   128
#define NPIDS  500
#define NDOCS  10000
#define DLEN   200
#define TOPK   100
#define VROW   (DLEN * HDIM)
#define NJOBS  (NB * NPIDS)
#define NBINS  (NDOCS + 1)
#define NENT   8192
#define SENT   0x7FFFFFFF

#define UNIT_BYTES 8192      // 32 tokens x 256 B
#define RING_UNITS 4
#define NUNITS     14        // 7 tiles x 2 k-halves

typedef _Float16 f16x8 __attribute__((ext_vector_type(8)));
typedef float    f32x16 __attribute__((ext_vector_type(16)));

// ---------------- Kernel 1: per-row sort + dedupe (dup -> -1) ----------------
__global__ __launch_bounds__(512) void dedupe_kernel(const int* __restrict__ pids,
                                                     const int* __restrict__ boundaries,
                                                     int* __restrict__ dpids) {
    __shared__ int s[512];
    const int b = blockIdx.x;
    const int t = threadIdx.x;
    const int lo = boundaries[0];

    int v = INT_MAX;
    if (t < NPIDS) {
        int p = pids[b * NPIDS + t] - lo;
        if (p < 0 || p >= NDOCS) p = -1;
        v = p;
    }
    s[t] = v;
    __syncthreads();

    for (int k = 2; k <= 512; k <<= 1) {
        for (int j = k >> 1; j > 0; j >>= 1) {
            int ixj = t ^ j;
            if (ixj > t) {
                int a = s[t], c = s[ixj];
                bool up = ((t & k) == 0);
                if ((a > c) == up) { s[t] = c; s[ixj] = a; }
            }
            __syncthreads();
        }
    }

    if (t < NPIDS) {
        int val = s[t];
        int o = val;
        if (val == INT_MAX) o = -1;
        else if (t > 0 && val == s[t - 1]) o = -1;
        dpids[b * NPIDS + t] = o;
    }
}

// ---------------- sort/pair pipeline (R13-verified) ----------------
__global__ __launch_bounds__(512) void init_kernel(int* __restrict__ counts,
                                                   int* __restrict__ counter,
                                                   int2* __restrict__ entries) {
    int i = blockIdx.x * 512 + threadIdx.x;
    if (i < NBINS) counts[i] = 0;
    if (i == 0) *counter = 0;
    if (i < NENT) entries[i] = make_int2(SENT, -1);
}

__global__ __launch_bounds__(512) void hist_kernel(const int* __restrict__ dpids,
                                                   int* __restrict__ counts) {
    int i = blockIdx.x * 512 + threadIdx.x;
    if (i < NJOBS) {
        int p = dpids[i];
        int key = (p < 0) ? NDOCS : p;
        atomicAdd(&counts[key], 1);
    }
}

__global__ __launch_bounds__(512) void scan_kernel(const int* __restrict__ counts,
                                                   int* __restrict__ offsets,
                                                   int* __restrict__ offsets0) {
    __shared__ int tmp[512];
    __shared__ int carry;
    const int t = threadIdx.x;
    if (t == 0) carry = 0;
    __syncthreads();

    for (int base = 0; base < NBINS; base += 512) {
        int x = (base + t < NBINS) ? counts[base + t] : 0;
        tmp[t] = x;
        __syncthreads();
        for (int off = 1; off < 512; off <<= 1) {
            int v = (t >= off) ? tmp[t - off] : 0;
            __syncthreads();
            tmp[t] += v;
            __syncthreads();
        }
        if (base + t < NBINS) {
            int e = carry + tmp[t] - x;
            offsets[base + t]  = e;
            offsets0[base + t] = e;
        }
        int btot = tmp[511];
        __syncthreads();
        if (t == 0) carry += btot;
        __syncthreads();
    }
}

__global__ __launch_bounds__(512) void scatter_kernel(const int* __restrict__ dpids,
                                                      int* __restrict__ offsets,
                                                      int* __restrict__ jobs) {
    int i = blockIdx.x * 512 + threadIdx.x;
    if (i < NJOBS) {
        int p = dpids[i];
        int key = (p < 0) ? NDOCS : p;
        int pos = atomicAdd(&offsets[key], 1);
        jobs[pos] = (key << 13) | i;
    }
}

__global__ __launch_bounds__(512) void pair_kernel(const int* __restrict__ jobs,
                                                   const int* __restrict__ offsets0,
                                                   int* __restrict__ counter,
                                                   int2* __restrict__ entries) {
    int i = blockIdx.x * 512 + threadIdx.x;
    if (i >= NJOBS) return;
    int e   = jobs[i];
    int key = e >> 13;
    int ja  = e & 8191;
    int rs  = offsets0[key];
    if (((i - rs) & 1) != 0) return;
    int jb = -1;
    if (i + 1 < NJOBS) {
        int e2 = jobs[i + 1];
        if ((e2 >> 13) == key) jb = e2 & 8191;
    }
    int pos = atomicAdd(counter, 1);
    entries[pos] = make_int2(key, (jb << 16) | ja);
}

// 2-limb fp16 RN split (R11-verified, absmax 0.0)
__device__ __forceinline__ void split2h(float a, _Float16& h, _Float16& m) {
    h = (_Float16)a;
    float r = a - (float)h;
    m = (_Float16)r;
}

__device__ __forceinline__ void split2h_pack8(const float4 c0, const float4 c1,
                                              f16x8& H, f16x8& M) {
    float f[8] = {c0.x, c0.y, c0.z, c0.w, c1.x, c1.y, c1.z, c1.w};
    f16x8 Ht, Mt;
    #pragma unroll
    for (int j = 0; j < 8; ++j) {
        _Float16 hh, mm;
        split2h(f[j], hh, mm);
        Ht[j] = hh; Mt[j] = mm;
    }
    H = Ht; M = Mt;
}

// ---------------- Kernel 2: MaxSim, V stream shared by 2 waves ----------------
// Block = 2 waves, one doc-pair entry. Both waves issue IDENTICAL staging
// (global_load_lds, same LDS dest, same bytes -> write races benign; second
// wave's requests are L2 hits). Wave 0 scores job A, wave 1 job B (single
// entry: wave 1 duplicates A, identical value). Each wave counts its OWN
// vmcnt; one raw s_barrier per unit keeps ring laps aligned (no vmcnt drain).
// Per-job numerics bit-identical to R11/R12.
__global__ __launch_bounds__(128, 2) void score_kernel(const float* __restrict__ qv,
                                                       const float* __restrict__ vectors,
                                                       const int2* __restrict__ entries,
                                                       float* __restrict__ scores) {
    const int t    = threadIdx.x;
    const int w    = t >> 6;
    const int lane = t & 63;
    const int row  = lane & 31;
    const int half = lane >> 5;

    const int bid = blockIdx.x;
    const int v   = (bid & 7) * (NENT / 8) + (bid >> 3);   // XCD swizzle, bijective

    const int2 ent = entries[v];
    const int pid  = ent.x;
    if (pid == SENT) return;
    const int ja = ent.y & 0xFFFF;
    const int jb = ent.y >> 16;
    if (pid >= NDOCS) {
        if (t == 0) {
            scores[ja] = -__builtin_inff();
            if (jb >= 0) scores[jb] = -__builtin_inff();
        }
        return;
    }

    const int job = (w == 0 || jb < 0) ? ja : jb;   // wave-uniform

    __shared__ __align__(16) unsigned char ring[RING_UNITS * UNIT_BYTES];

    // ---- this wave's Q limbs ----
    f16x8 qh[8], qm[8];
    {
        const float* qb = qv + ((size_t)(job / NPIDS) * QLEN + row) * HDIM + half * 8;
        #pragma unroll
        for (int ks = 0; ks < 8; ++ks) {
            const float4 a0 = *(const float4*)(qb + ks * 16);
            const float4 a1 = *(const float4*)(qb + ks * 16 + 4);
            split2h_pack8(a0, a1, qh[ks], qm[ks]);
        }
    }
    __builtin_amdgcn_sched_barrier(0);

    const char* vcand = (const char*)(vectors + (size_t)pid * VROW);

    auto stage = [&](int u) {
        const int tile = u >> 1, seg = u & 1;
        const int sbase = (u & 3) * UNIT_BYTES;
        #pragma unroll
        for (int i = 0; i < 8; ++i) {
            const int p  = i * 1024 + lane * 16;
            const int tp = p >> 8;
            int tg = tile * 32 + tp;
            if (tg > DLEN - 1) tg = DLEN - 1;
            const unsigned soff = (unsigned)tg * 512u + (unsigned)seg * 256u
                                + (unsigned)((p & 255) ^ ((tp & 7) << 4));
            __builtin_amdgcn_global_load_lds(
                (const __attribute__((address_space(1))) void*)(vcand + soff),
                (__attribute__((address_space(3))) void*)(&ring[sbase + i * 1024]),
                16, 0, 0);
        }
    };

    float rmax[16];
    #pragma unroll
    for (int j = 0; j < 16; ++j) rmax[j] = -FLT_MAX;

    f32x16 acc;

    stage(0); stage(1); stage(2); stage(3);

    #pragma unroll
    for (int u = 0; u < NUNITS; ++u) {
        // wait for THIS wave's stage of unit u (FIFO; both waves issue equally)
        if (u <= 10)      asm volatile("s_waitcnt vmcnt(24)" ::: "memory");
        else if (u == 11) asm volatile("s_waitcnt vmcnt(16)" ::: "memory");
        else if (u == 12) asm volatile("s_waitcnt vmcnt(8)"  ::: "memory");
        else              asm volatile("s_waitcnt vmcnt(0)"  ::: "memory");
        __builtin_amdgcn_sched_barrier(0);

        if ((u & 1) == 0) {
            #pragma unroll
            for (int j = 0; j < 16; ++j) acc[j] = 0.0f;
        }

        const int ubase = (u & 3) * UNIT_BYTES;
        const int seg   = u & 1;
        const int swz   = (row & 7) << 4;
        #pragma unroll
        for (int k2 = 0; k2 < 4; ++k2) {
            const int ks   = seg * 4 + k2;
            const int off0 = row * 256 + k2 * 64 + half * 32;
            const float4 c0 = *(const float4*)&ring[ubase + (off0 ^ swz)];
            const float4 c1 = *(const float4*)&ring[ubase + ((off0 + 16) ^ swz)];
            f16x8 vh, vm;
            split2h_pack8(c0, c1, vh, vm);
            acc = __builtin_amdgcn_mfma_f32_32x32x16_f16(qh[ks], vh, acc, 0, 0, 0);
            acc = __builtin_amdgcn_mfma_f32_32x32x16_f16(qh[ks], vm, acc, 0, 0, 0);
            acc = __builtin_amdgcn_mfma_f32_32x32x16_f16(qm[ks], vh, acc, 0, 0, 0);
        }

        if (u & 1) {
            #pragma unroll
            for (int j = 0; j < 16; ++j) rmax[j] = fmaxf(rmax[j], acc[j]);
        }

        // both waves done reading slot u&3 before either re-stages it
        __builtin_amdgcn_sched_barrier(0);
        asm volatile("s_waitcnt lgkmcnt(0)" ::: "memory");
        __builtin_amdgcn_s_barrier();
        __builtin_amdgcn_sched_barrier(0);
        if (u + 4 < NUNITS) stage(u + 4);
    }

    double dsum = 0.0;
    #pragma unroll
    for (int j = 0; j < 16; ++j) {
        float m = rmax[j];
        m = fmaxf(m, __shfl_xor(m, 1));
        m = fmaxf(m, __shfl_xor(m, 2));
        m = fmaxf(m, __shfl_xor(m, 4));
        m = fmaxf(m, __shfl_xor(m, 8));
        m = fmaxf(m, __shfl_xor(m, 16));
        dsum += (double)m;
    }
    dsum += __shfl_xor(dsum, 32);
    if (lane == 0) scores[job] = (float)dsum;   // dup write (single entry) benign
}

// ---------------- Kernel 3: per-batch top-100 (sorted desc) ----------------
__global__ __launch_bounds__(512) void topk_kernel(const float* __restrict__ scores,
                                                   const int* __restrict__ dpids,
                                                   const int* __restrict__ boundaries,
                                                   float* __restrict__ out) {
    __shared__ float ss[512];
    __shared__ int   sp[512];
    const int b = blockIdx.x;
    const int t = threadIdx.x;
    const int lo = boundaries[0];

    float sc = -__builtin_inff();
    int   p  = -1;
    if (t < NPIDS) {
        p = dpids[b * NPIDS + t];
        sc = (p < 0) ? -__builtin_inff() : scores[b * NPIDS + t];
    }
    ss[t] = sc;
    sp[t] = p;
    __syncthreads();

    for (int k = 2; k <= 512; k <<= 1) {
        for (int j = k >> 1; j > 0; j >>= 1) {
            int ixj = t ^ j;
            if (ixj > t) {
                float a = ss[t], c = ss[ixj];
                bool down = ((t & k) == 0);
                bool swap = down ? (a < c) : (a > c);
                if (swap) {
                    int pa = sp[t], pc = sp[ixj];
                    ss[t] = c;   ss[ixj] = a;
                    sp[t] = pc;  sp[ixj] = pa;
                }
            }
            __syncthreads();
        }
    }

    if (t < TOPK) {
        out[b * TOPK + t] = ss[t];
        int pp = sp[t];
        out[NB * TOPK + b * TOPK + t] = (pp >= 0) ? (float)(pp + lo) : -1.0f;
    }
}

// ---------------- launch ----------------
extern "C" void kernel_launch(void* const* d_in, const int* in_sizes, int n_in,
                              void* d_out, int out_size, void* d_ws, size_t ws_size,
                              hipStream_t stream) {
    const float* qv        = (const float*)d_in[0];
    const int*   pids      = (const int*)d_in[1];
    const float* vectors   = (const float*)d_in[2];
    const int*   boundaries= (const int*)d_in[3];

    char* ws = (char*)d_ws;
    int*   dpids    = (int*)(ws);
    float* scores   = (float*)(ws + 32768);
    int*   counts   = (int*)(ws + 65536);
    int*   offsets  = (int*)(ws + 114688);
    int*   offsets0 = (int*)(ws + 163840);
    int*   jobs     = (int*)(ws + 212992);
    int2*  entries  = (int2*)(ws + 262144);
    int*   counter  = (int*)(ws + 327680);

    dedupe_kernel <<<NB, 512, 0, stream>>>(pids, boundaries, dpids);
    init_kernel   <<<(NBINS + 511) / 512, 512, 0, stream>>>(counts, counter, entries);
    hist_kernel   <<<(NJOBS + 511) / 512, 512, 0, stream>>>(dpids, counts);
    scan_kernel   <<<1, 512, 0, stream>>>(counts, offsets, offsets0);
    scatter_kernel<<<(NJOBS + 511) / 512, 512, 0, stream>>>(dpids, offsets, jobs);
    pair_kernel   <<<(NJOBS + 511) / 512, 512, 0, stream>>>(jobs, offsets0, counter, entries);
    score_kernel  <<<NENT, 128, 0, stream>>>(qv, vectors, entries, scores);
    topk_kernel   <<<NB, 512, 0, stream>>>(scores, dpids, boundaries, (float*)d_out);
}

// Round 15
// 163.723 us; speedup vs baseline: 1.4915x; 1.4915x over previous
//
#include <hip/hip_runtime.h>
#include <float.h>
#include <limits.h>

#define NB     16
#define QLEN   32
#define HDIM   128
#define NPIDS  500
#define NDOCS  10000
#define DLEN   200
#define TOPK   100
#define VROW   (DLEN * HDIM)

typedef __bf16 bf16x8 __attribute__((ext_vector_type(8)));
typedef float  f32x16 __attribute__((ext_vector_type(16)));

// ---------------- Kernel 1: per-row sort + dedupe (dup -> -1) ----------------
__global__ __launch_bounds__(512) void dedupe_kernel(const int* __restrict__ pids,
                                                     const int* __restrict__ boundaries,
                                                     int* __restrict__ dpids) {
    __shared__ int s[512];
    const int b = blockIdx.x;
    const int t = threadIdx.x;
    const int lo = boundaries[0];

    int v = INT_MAX;
    if (t < NPIDS) {
        int p = pids[b * NPIDS + t] - lo;
        if (p < 0 || p >= NDOCS) p = -1;
        v = p;
    }
    s[t] = v;
    __syncthreads();

    for (int k = 2; k <= 512; k <<= 1) {
        for (int j = k >> 1; j > 0; j >>= 1) {
            int ixj = t ^ j;
            if (ixj > t) {
                int a = s[t], c = s[ixj];
                bool up = ((t & k) == 0);
                if ((a > c) == up) { s[t] = c; s[ixj] = a; }
            }
            __syncthreads();
        }
    }

    if (t < NPIDS) {
        int val = s[t];
        int o = val;
        if (val == INT_MAX) o = -1;
        else if (t > 0 && val == s[t - 1]) o = -1;
        dpids[b * NPIDS + t] = o;
    }
}

// 3-way bf16 split (round-to-nearest) — the R4/R7-verified path (absmax 0.0).
// r1 = a - (float)h and r2 = r1 - (float)m are exact (Sterbenz).
__device__ __forceinline__ void split3(float a, __bf16& h, __bf16& m, __bf16& l) {
    h = (__bf16)a;
    float r1 = a - (float)h;
    m = (__bf16)r1;
    float r2 = r1 - (float)m;
    l = (__bf16)r2;
}

__device__ __forceinline__ void split3_pack8(const float4 c0, const float4 c1,
                                             bf16x8& H, bf16x8& M, bf16x8& L) {
    float f[8] = {c0.x, c0.y, c0.z, c0.w, c1.x, c1.y, c1.z, c1.w};
    bf16x8 Ht, Mt, Lt;
    #pragma unroll
    for (int j = 0; j < 8; ++j) {
        __bf16 hh, mm, ll;
        split3(f[j], hh, mm, ll);
        Ht[j] = hh; Mt[j] = mm; Lt[j] = ll;
    }
    H = Ht; M = Mt; L = Lt;
}

// ---------------- Kernel 2: MaxSim via split-bf16 MFMA + depth-4 prefetch ----------------
// R7 configuration — best measured (164.1 µs, absmax 0.0).
// One wave per 2 consecutive candidates (same batch: 500 even, pairs aligned).
// Q limbs stationary in registers. RN split3 limbs, MFMA order hh,hm,mh,hl,lh.
// Depth-4 circular register prefetch over 32B chunks.
__global__ __launch_bounds__(256, 2) void score_kernel(const float* __restrict__ qv,
                                                       const float* __restrict__ vectors,
                                                       const int* __restrict__ dpids,
                                                       float* __restrict__ scores) {
    const int t    = threadIdx.x;
    const int w    = t >> 6;
    const int lane = t & 63;
    const int row  = lane & 31;     // q-row for A, token-in-tile for B
    const int half = lane >> 5;     // k-half selector

    const int cbase = (blockIdx.x * 4 + w) * 2;
    const int b     = cbase / NPIDS;

    // ---- load + split Q fragments (stationary for both candidates) ----
    bf16x8 qh[8], qm[8], ql[8];
    {
        const float* qb = qv + ((size_t)b * QLEN + row) * HDIM + half * 8;
        #pragma unroll
        for (int ks = 0; ks < 8; ++ks) {
            const float4 a0 = *(const float4*)(qb + ks * 16);
            const float4 a1 = *(const float4*)(qb + ks * 16 + 4);
            split3_pack8(a0, a1, qh[ks], qm[ks], ql[ks]);
        }
    }

    for (int ci = 0; ci < 2; ++ci) {
        const int c   = cbase + ci;
        const int pid = dpids[c];
        if (pid < 0) {
            if (lane == 0) scores[c] = -__builtin_inff();
            continue;
        }

        const float* vb = vectors + (size_t)pid * VROW + half * 8;

        float rmax[16];
        #pragma unroll
        for (int j = 0; j < 16; ++j) rmax[j] = -FLT_MAX;

        // ---- prologue: prefetch chunks 0..3 (tile 0, ks 0..3) ----
        const float* vt0 = vb + (size_t)row * HDIM;   // tile 0: tok = row < 200
        float4 pf[4][2];
        #pragma unroll
        for (int s = 0; s < 4; ++s) {
            pf[s][0] = *(const float4*)(vt0 + s * 16);
            pf[s][1] = *(const float4*)(vt0 + s * 16 + 4);
        }

        #pragma unroll 1
        for (int tile = 0; tile < 7; ++tile) {
            int tok = tile * 32 + row;
            if (tok > DLEN - 1) tok = DLEN - 1;            // dup token 199: max-safe
            const float* vt = vb + (size_t)tok * HDIM;
            int tokn = (tile + 1) * 32 + row;
            if (tokn > DLEN - 1) tokn = DLEN - 1;
            const float* vtn = vb + (size_t)tokn * HDIM;   // next tile base

            f32x16 acc;
            #pragma unroll
            for (int j = 0; j < 16; ++j) acc[j] = 0.0f;

            #pragma unroll
            for (int ks = 0; ks < 8; ++ks) {
                const int slot = ks & 3;                   // compile-time in unroll
                const float4 c0 = pf[slot][0];
                const float4 c1 = pf[slot][1];

                // issue chunk +4 into the freed slot
                if (ks < 4) {
                    pf[slot][0] = *(const float4*)(vt + (ks + 4) * 16);
                    pf[slot][1] = *(const float4*)(vt + (ks + 4) * 16 + 4);
                } else if (tile < 6) {
                    pf[slot][0] = *(const float4*)(vtn + (ks - 4) * 16);
                    pf[slot][1] = *(const float4*)(vtn + (ks - 4) * 16 + 4);
                }

                bf16x8 vh, vm, vl;
                split3_pack8(c0, c1, vh, vm, vl);
                acc = __builtin_amdgcn_mfma_f32_32x32x16_bf16(qh[ks], vh, acc, 0, 0, 0);
                acc = __builtin_amdgcn_mfma_f32_32x32x16_bf16(qh[ks], vm, acc, 0, 0, 0);
                acc = __builtin_amdgcn_mfma_f32_32x32x16_bf16(qm[ks], vh, acc, 0, 0, 0);
                acc = __builtin_amdgcn_mfma_f32_32x32x16_bf16(qh[ks], vl, acc, 0, 0, 0);
                acc = __builtin_amdgcn_mfma_f32_32x32x16_bf16(ql[ks], vh, acc, 0, 0, 0);
            }

            #pragma unroll
            for (int j = 0; j < 16; ++j) rmax[j] = fmaxf(rmax[j], acc[j]);
        }

        // cross-lane max over the 32 token-columns per q-row, then double-sum.
        double dsum = 0.0;
        #pragma unroll
        for (int j = 0; j < 16; ++j) {
            float m = rmax[j];
            m = fmaxf(m, __shfl_xor(m, 1));
            m = fmaxf(m, __shfl_xor(m, 2));
            m = fmaxf(m, __shfl_xor(m, 4));
            m = fmaxf(m, __shfl_xor(m, 8));
            m = fmaxf(m, __shfl_xor(m, 16));
            dsum += (double)m;
        }
        dsum += __shfl_xor(dsum, 32);
        if (lane == 0) scores[c] = (float)dsum;
    }
}

// ---------------- Kernel 3: per-batch top-100 (sorted desc) ----------------
__global__ __launch_bounds__(512) void topk_kernel(const float* __restrict__ scores,
                                                   const int* __restrict__ dpids,
                                                   const int* __restrict__ boundaries,
                                                   float* __restrict__ out) {
    __shared__ float ss[512];
    __shared__ int   sp[512];
    const int b = blockIdx.x;
    const int t = threadIdx.x;
    const int lo = boundaries[0];

    float sc = -__builtin_inff();
    int   p  = -1;
    if (t < NPIDS) {
        p = dpids[b * NPIDS + t];
        sc = (p < 0) ? -__builtin_inff() : scores[b * NPIDS + t];
    }
    ss[t] = sc;
    sp[t] = p;
    __syncthreads();

    for (int k = 2; k <= 512; k <<= 1) {
        for (int j = k >> 1; j > 0; j >>= 1) {
            int ixj = t ^ j;
            if (ixj > t) {
                float a = ss[t], c = ss[ixj];
                bool down = ((t & k) == 0);
                bool swap = down ? (a < c) : (a > c);
                if (swap) {
                    int pa = sp[t], pc = sp[ixj];
                    ss[t] = c;   ss[ixj] = a;
                    sp[t] = pc;  sp[ixj] = pa;
                }
            }
            __syncthreads();
        }
    }

    if (t < TOPK) {
        out[b * TOPK + t] = ss[t];
        int pp = sp[t];
        out[NB * TOPK + b * TOPK + t] = (pp >= 0) ? (float)(pp + lo) : -1.0f;
    }
}

// ---------------- launch ----------------
extern "C" void kernel_launch(void* const* d_in, const int* in_sizes, int n_in,
                              void* d_out, int out_size, void* d_ws, size_t ws_size,
                              hipStream_t stream) {
    const float* qv        = (const float*)d_in[0];
    const int*   pids      = (const int*)d_in[1];
    const float* vectors   = (const float*)d_in[2];
    const int*   boundaries= (const int*)d_in[3];

    int*   dpids  = (int*)d_ws;
    float* scores = (float*)((char*)d_ws + 32768);

    dedupe_kernel<<<NB, 512, 0, stream>>>(pids, boundaries, dpids);
    score_kernel <<<(NB * NPIDS) / 8, 256, 0, stream>>>(qv, vectors, dpids, scores);
    topk_kernel  <<<NB, 512, 0, stream>>>(scores, dpids, boundaries, (float*)d_out);
}